// Round 10
// baseline (544.605 us; speedup 1.0000x reference)
//
#include <hip/hip_runtime.h>
#include <math.h>

// ---------------------------------------------------------------------------
// NequIP fused, round 9: widen MFMA:mem issue ratio (4 n-tiles per group).
//
// R8 post-mortem: occupancy 22->45% changed nothing (355 vs 373us) => not a
// TLP problem. Per-kk shape was 3 mem : 2 MFMA with tight producer->consumer
// distance; every wave stalls at the same waitcnts. This round widens the
// passing R8 loop minimally: groups of 4 n-tiles, kk inside:
//   per kk: 2 A ds_reads (shared x4) + 4 B loads -> 8 MFMAs
//   (A-LDS traffic /4, 8 independent acc chains, 6:8 mem:MFMA issue mix)
// Epilogue/contraction = R8 verbatim looped over gi. ~110 regs @ 4 waves/EU.
// ---------------------------------------------------------------------------

typedef __attribute__((ext_vector_type(8))) short s8v;    // 8 x bf16 (4 VGPR)
typedef __attribute__((ext_vector_type(4))) float f4v;    // 16x16 acc (4 f32)
typedef unsigned short ushort_t;
typedef unsigned int uint_t;

#define NTHR 512
#define TE 64

__device__ __forceinline__ ushort_t f2bf(float x) {
    uint_t u = __float_as_uint(x);
    u += 0x7fffu + ((u >> 16) & 1u);   // round-to-nearest-even
    return (ushort_t)(u >> 16);
}

// W2 [256][1024] fp32 -> W2bf [1024][256] bf16 (transposed, k-contiguous).
__global__ void conv_w2(const float* __restrict__ W2, ushort_t* __restrict__ W2bf) {
    int idx = blockIdx.x * 256 + threadIdx.x;      // 65536 threads, 4 k each
    int n  = idx & 1023;
    int k4 = (idx >> 10) << 2;
    uint_t lo = (uint_t)f2bf(W2[(size_t)(k4 + 0) * 1024 + n]) |
                ((uint_t)f2bf(W2[(size_t)(k4 + 1) * 1024 + n]) << 16);
    uint_t hi = (uint_t)f2bf(W2[(size_t)(k4 + 2) * 1024 + n]) |
                ((uint_t)f2bf(W2[(size_t)(k4 + 3) * 1024 + n]) << 16);
    ((uint2*)W2bf)[(n * 256 + k4) >> 2] = make_uint2(lo, hi);
}

// ---------------- CSR build ----------------
__global__ void hist_kernel(const int* __restrict__ edst, int* __restrict__ counts, int E) {
    int i = blockIdx.x * 256 + threadIdx.x;
    if (i < E) atomicAdd(&counts[edst[i]], 1);
}

__global__ __launch_bounds__(1024)
void scan_kernel(const int* __restrict__ counts, int* __restrict__ offsets, int N) {
    __shared__ int sdata[1024];
    const int t = threadIdx.x;
    const int C = (N + 1023) / 1024;
    const int lo = t * C;
    const int hi = min(lo + C, N);
    int sum = 0;
    for (int i = lo; i < hi; ++i) sum += counts[i];
    sdata[t] = sum;
    __syncthreads();
    for (int s = 1; s < 1024; s <<= 1) {
        int v = (t >= s) ? sdata[t - s] : 0;
        __syncthreads();
        sdata[t] += v;
        __syncthreads();
    }
    int run = sdata[t] - sum;
    for (int i = lo; i < hi; ++i) { offsets[i] = run; run += counts[i]; }
    if (t == 1023) offsets[N] = run;
}

__global__ void fill_kernel(const int* __restrict__ edst,
                            const int* __restrict__ offsets,
                            int* __restrict__ cursor,
                            int* __restrict__ elist, int E) {
    int i = blockIdx.x * 256 + threadIdx.x;
    if (i < E) {
        int d = edst[i];
        int pos = offsets[d] + atomicAdd(&cursor[d], 1);
        elist[pos] = i;
    }
}

// ---------------- gather: one wave per node ----------------
__global__ __launch_bounds__(256)
void gather_kernel(const float* __restrict__ F,
                   const int* __restrict__ offsets,
                   const int* __restrict__ elist,
                   float* __restrict__ out, int N) {
    const int lane = threadIdx.x & 63;
    const int node = (blockIdx.x * 256 + threadIdx.x) >> 6;
    if (node >= N) return;
    const int base = offsets[node];
    const int end  = offsets[node + 1];
    float acc = 0.f;
    for (int j0 = base; j0 < end; j0 += 64) {
        const int rem = min(64, end - j0);
        int myeid = (lane < rem) ? elist[j0 + lane] : 0;
        int j = 0;
        for (; j + 4 <= rem; j += 4) {
            const int a0 = __shfl(myeid, j    );
            const int a1 = __shfl(myeid, j + 1);
            const int a2 = __shfl(myeid, j + 2);
            const int a3 = __shfl(myeid, j + 3);
            const float r0 = F[(size_t)a0 * 64 + lane];
            const float r1 = F[(size_t)a1 * 64 + lane];
            const float r2 = F[(size_t)a2 * 64 + lane];
            const float r3 = F[(size_t)a3 * 64 + lane];
            acc += (r0 + r1) + (r2 + r3);
        }
        for (; j < rem; ++j) {
            const int a = __shfl(myeid, j);
            acc += F[(size_t)a * 64 + lane];
        }
    }
    out[(size_t)node * 64 + lane] = acc;
}

// ---------------- main fused edge kernel (512 thr, 8 waves) ----------------
__global__ __attribute__((amdgpu_flat_work_group_size(NTHR, NTHR),
                          amdgpu_waves_per_eu(4, 4)))
void nequip_mfma(const float* __restrict__ nodef,
                 const float* __restrict__ eattr,
                 const float* __restrict__ eemb,
                 const float* __restrict__ W1,
                 const float* __restrict__ b1,
                 const ushort_t* __restrict__ W2bf,
                 const float* __restrict__ b2,
                 const int* __restrict__ esrc,
                 float* __restrict__ F,
                 int E, float CC)
{
    __shared__ __align__(16) ushort_t sAu[TE * 256];   // 32 KB h bf16, A-frag order
    __shared__ __align__(16) float sB2[1024];          // 4 KB
    __shared__ __align__(16) float sEmb[TE * 18];      // 4.5 KB
    __shared__ __align__(16) float sCss[16 * 64];      // coef[i][e] = CC*y0*s
    __shared__ __align__(16) float sCvv[16 * 64];      // CC/sqrt3*(y1.v)
    __shared__ __align__(16) float sCsv[16 * 64];      // CC*s
    __shared__ __align__(16) float sCvs[48 * 64];      // [(i*3+a)][e] = CC*y0*v
    __shared__ __align__(16) float sAttrT[4 * 64];     // [c][e]
    __shared__ __align__(16) float resSS[64 * 16];     // ss partial (4 KB)
    __shared__ __align__(16) float resSV[64 * 16];     // sv partial (4 KB)

    const int t  = threadIdx.x;
    const int e0 = blockIdx.x * TE;

    // ---------------- phase 1: staging + coef tables ----------------
    ((float2*)sB2)[t] = ((const float2*)b2)[t];        // 512 x float2 = 1024
    for (int idx = t; idx < TE * 18; idx += NTHR) {
        size_t g = (size_t)e0 * 18 + idx;
        sEmb[idx] = (g < (size_t)E * 18) ? eemb[g] : 0.f;
    }
    if (t < TE) {
        int ge = e0 + t;
        float4 a = make_float4(0.f, 0.f, 0.f, 0.f);
        if (ge < E) a = *(const float4*)(eattr + (size_t)ge * 4);
        sAttrT[0 * 64 + t] = a.x; sAttrT[1 * 64 + t] = a.y;
        sAttrT[2 * 64 + t] = a.z; sAttrT[3 * 64 + t] = a.w;
    }
    if (t < 256) {   // thread t -> edge e = t>>2, i-quad iq = t&3
        const int e = t >> 2, iq = t & 3;
        const int ge = e0 + e;
        const bool ok = ge < E;
        float y0 = 0.f, y1x = 0.f, y1y = 0.f, y1z = 0.f;
        int src = 0;
        if (ok) {
            float4 a = *(const float4*)(eattr + (size_t)ge * 4);
            y0 = a.x; y1x = a.y; y1y = a.z; y1z = a.w;
            src = esrc[ge];
        }
        const float* xp = nodef + (size_t)src * 64;
        float4 z = make_float4(0.f, 0.f, 0.f, 0.f);
        float4 sv = ok ? *(const float4*)(xp + iq * 4) : z;
        float4 v0 = ok ? *(const float4*)(xp + 16 + iq * 12) : z;
        float4 v1 = ok ? *(const float4*)(xp + 16 + iq * 12 + 4) : z;
        float4 v2 = ok ? *(const float4*)(xp + 16 + iq * 12 + 8) : z;
        const float K3 = CC * 0.57735026918962576f;   // CC/sqrt(3)
        float sarr[4] = { sv.x, sv.y, sv.z, sv.w };
        float varr[12] = { v0.x, v0.y, v0.z, v0.w, v1.x, v1.y, v1.z, v1.w,
                           v2.x, v2.y, v2.z, v2.w };
        #pragma unroll
        for (int j = 0; j < 4; ++j) {
            const int i = iq * 4 + j;
            const float s  = sarr[j];
            const float vx = varr[j * 3 + 0], vy = varr[j * 3 + 1], vz = varr[j * 3 + 2];
            sCss[i * 64 + e] = CC * y0 * s;
            sCvv[i * 64 + e] = K3 * (y1x * vx + y1y * vy + y1z * vz);
            sCsv[i * 64 + e] = CC * s;
            sCvs[(i * 3 + 0) * 64 + e] = CC * y0 * vx;
            sCvs[(i * 3 + 1) * 64 + e] = CC * y0 * vy;
            sCvs[(i * 3 + 2) * 64 + e] = CC * y0 * vz;
        }
    }
    __syncthreads();

    // ---- phase 2: h = silu(emb@W1+b1) -> sAu, 16x16x32 A-frag order ----
    {
        const int p = t & 127;         // column pair p -> cols 2p, 2p+1
        const int equad = t >> 7;      // 0..3: e = equad*16 + er
        const int n0 = 2 * p;
        float w1a[18], w1b[18];
        #pragma unroll
        for (int m = 0; m < 18; ++m) {
            float2 wv = *(const float2*)(W1 + m * 256 + n0);
            w1a[m] = wv.x; w1b[m] = wv.y;
        }
        const float2 bv = *(const float2*)(b1 + n0);
        const int kk = p >> 4;                       // k-iter (0..7)
        const int lhi = 16 * ((p >> 2) & 3);
        const int wsub = p & 3;                      // uint slot within 16B frag
        uint_t* sA32 = (uint_t*)sAu;
        for (int er = 0; er < 16; ++er) {
            const int e = equad * 16 + er;
            float a0 = bv.x, a1 = bv.y;
            const float* ep = sEmb + e * 18;
            #pragma unroll
            for (int m = 0; m < 18; ++m) {
                const float em = ep[m];
                a0 = fmaf(em, w1a[m], a0);
                a1 = fmaf(em, w1b[m], a1);
            }
            a0 = a0 / (1.f + __expf(-a0));          // silu
            a1 = a1 / (1.f + __expf(-a1));
            const uint_t pk = (uint_t)f2bf(a0) | ((uint_t)f2bf(a1) << 16);
            const int lane_sw = ((e & 15) + lhi) ^ kk;
            sA32[(((e >> 4) * 8 + kk) * 64 + lane_sw) * 4 + wsub] = pk;
        }
    }
    __syncthreads();

    // ---------------- phase 3: per-wave, 4 groups of 4 n-tiles ----------------
    const int lane  = t & 63;
    const int w     = t >> 6;         // 0..7
    const int mhalf = w & 1;          // e-half
    const int slab  = w >> 1;         // 0:ss 1:vv 2:sv 3:vs
    const int jj    = lane & 15;
    const int q4    = lane >> 4;
    const int eb0   = mhalf * 32 + q4 * 4;
    const int eb1   = eb0 + 16;

    const ushort_t* Bl = W2bf + (size_t)jj * 256 + q4 * 8;  // + nb*256 + kk*32

    // per-slab register partials
    float p0[4] = {0.f, 0.f, 0.f, 0.f}, p1[4] = {0.f, 0.f, 0.f, 0.f};
    float pV0[3][4] = {{0.f}}, pV1[3][4] = {{0.f}};   // only slab 3 uses

    #pragma unroll 1
    for (int g = 0; g < 4; ++g) {
        f4v acc0[4], acc1[4];
        #pragma unroll
        for (int gi = 0; gi < 4; ++gi) {
            const float bz = sB2[slab * 256 + (g * 4 + gi) * 16 + jj];
            f4v z; z[0] = bz; z[1] = bz; z[2] = bz; z[3] = bz;
            acc0[gi] = z; acc1[gi] = z;
        }
        #pragma unroll
        for (int kk = 0; kk < 8; ++kk) {
            const s8v a0 = *(const s8v*)(sAu + (((mhalf * 2 + 0) * 8 + kk) * 64 + (lane ^ kk)) * 8);
            const s8v a1 = *(const s8v*)(sAu + (((mhalf * 2 + 1) * 8 + kk) * 64 + (lane ^ kk)) * 8);
            #pragma unroll
            for (int gi = 0; gi < 4; ++gi) {
                const int nb = slab * 256 + (g * 4 + gi) * 16;
                const s8v b = *(const s8v*)(Bl + (size_t)nb * 256 + kk * 32);
                acc0[gi] = __builtin_amdgcn_mfma_f32_16x16x32_bf16(a0, b, acc0[gi], 0, 0, 0);
                acc1[gi] = __builtin_amdgcn_mfma_f32_16x16x32_bf16(a1, b, acc1[gi], 0, 0, 0);
            }
        }
        // contraction for the 4 finished tiles (same formulas as R8, i = g*4+gi)
        #pragma unroll
        for (int gi = 0; gi < 4; ++gi) {
            const int i = g * 4 + gi;
            if (slab == 0 || slab == 1) {
                const float* C = (slab == 0) ? sCss : sCvv;
                const float4 c0 = *(const float4*)(C + i * 64 + eb0);
                const float4 c1 = *(const float4*)(C + i * 64 + eb1);
                p0[0] = fmaf(c0.x, acc0[gi][0], p0[0]); p0[1] = fmaf(c0.y, acc0[gi][1], p0[1]);
                p0[2] = fmaf(c0.z, acc0[gi][2], p0[2]); p0[3] = fmaf(c0.w, acc0[gi][3], p0[3]);
                p1[0] = fmaf(c1.x, acc1[gi][0], p1[0]); p1[1] = fmaf(c1.y, acc1[gi][1], p1[1]);
                p1[2] = fmaf(c1.z, acc1[gi][2], p1[2]); p1[3] = fmaf(c1.w, acc1[gi][3], p1[3]);
            } else if (slab == 2) {
                const float4 c0 = *(const float4*)(sCsv + i * 64 + eb0);
                const float4 c1 = *(const float4*)(sCsv + i * 64 + eb1);
                p0[0] = fmaf(c0.x, acc0[gi][0], p0[0]); p0[1] = fmaf(c0.y, acc0[gi][1], p0[1]);
                p0[2] = fmaf(c0.z, acc0[gi][2], p0[2]); p0[3] = fmaf(c0.w, acc0[gi][3], p0[3]);
                p1[0] = fmaf(c1.x, acc1[gi][0], p1[0]); p1[1] = fmaf(c1.y, acc1[gi][1], p1[1]);
                p1[2] = fmaf(c1.z, acc1[gi][2], p1[2]); p1[3] = fmaf(c1.w, acc1[gi][3], p1[3]);
            } else {
                #pragma unroll
                for (int a = 0; a < 3; ++a) {
                    const float4 c0 = *(const float4*)(sCvs + (i * 3 + a) * 64 + eb0);
                    const float4 c1 = *(const float4*)(sCvs + (i * 3 + a) * 64 + eb1);
                    pV0[a][0] = fmaf(c0.x, acc0[gi][0], pV0[a][0]);
                    pV0[a][1] = fmaf(c0.y, acc0[gi][1], pV0[a][1]);
                    pV0[a][2] = fmaf(c0.z, acc0[gi][2], pV0[a][2]);
                    pV0[a][3] = fmaf(c0.w, acc0[gi][3], pV0[a][3]);
                    pV1[a][0] = fmaf(c1.x, acc1[gi][0], pV1[a][0]);
                    pV1[a][1] = fmaf(c1.y, acc1[gi][1], pV1[a][1]);
                    pV1[a][2] = fmaf(c1.z, acc1[gi][2], pV1[a][2]);
                    pV1[a][3] = fmaf(c1.w, acc1[gi][3], pV1[a][3]);
                }
            }
        }
    }

    // publish ss / sv partials
    if (slab == 0) {
        #pragma unroll
        for (int q = 0; q < 4; ++q) {
            resSS[(eb0 + q) * 16 + jj] = p0[q];
            resSS[(eb1 + q) * 16 + jj] = p1[q];
        }
    } else if (slab == 2) {
        #pragma unroll
        for (int q = 0; q < 4; ++q) {
            resSV[(eb0 + q) * 16 + jj] = p0[q];
            resSV[(eb1 + q) * 16 + jj] = p1[q];
        }
    }
    __syncthreads();

    // combine + store directly to F
    if (slab == 1) {          // out_s = resSS + vv partial
        #pragma unroll
        for (int q = 0; q < 4; ++q) {
            const int eA = eb0 + q, eB = eb1 + q;
            if (e0 + eA < E) F[(size_t)(e0 + eA) * 64 + jj] = resSS[eA * 16 + jj] + p0[q];
            if (e0 + eB < E) F[(size_t)(e0 + eB) * 64 + jj] = resSS[eB * 16 + jj] + p1[q];
        }
    } else if (slab == 3) {   // out_v[a] = y1[a]*resSV + vs partial
        #pragma unroll
        for (int q = 0; q < 4; ++q) {
            const int eA = eb0 + q, eB = eb1 + q;
            const float svA = resSV[eA * 16 + jj];
            const float svB = resSV[eB * 16 + jj];
            #pragma unroll
            for (int a = 0; a < 3; ++a) {
                const float yA = sAttrT[(1 + a) * 64 + eA];
                const float yB = sAttrT[(1 + a) * 64 + eB];
                if (e0 + eA < E)
                    F[(size_t)(e0 + eA) * 64 + 16 + jj * 3 + a] = fmaf(yA, svA, pV0[a][q]);
                if (e0 + eB < E)
                    F[(size_t)(e0 + eB) * 64 + 16 + jj * 3 + a] = fmaf(yB, svB, pV1[a][q]);
            }
        }
    }
}

extern "C" void kernel_launch(void* const* d_in, const int* in_sizes, int n_in,
                              void* d_out, int out_size, void* d_ws, size_t ws_size,
                              hipStream_t stream)
{
    const float* node_features = (const float*)d_in[0];
    const float* edge_attr     = (const float*)d_in[1];
    const float* edge_emb      = (const float*)d_in[2];
    const float* W1            = (const float*)d_in[3];
    const float* b1            = (const float*)d_in[4];
    const float* W2            = (const float*)d_in[5];
    const float* b2            = (const float*)d_in[6];
    const int*   edge_src      = (const int*)d_in[7];
    const int*   edge_dst      = (const int*)d_in[8];
    float*       out           = (float*)d_out;

    const int E = in_sizes[7];
    const int N = out_size / 64;
    const float num_neigh = (float)E / (float)N;
    const float CC = 0.17677669529663689f / sqrtf(num_neigh);

    // ---- workspace layout ----
    char* ws = (char*)d_ws;
    size_t off = 0;
    auto alloc = [&](size_t bytes) { char* p = ws + off; off = (off + bytes + 255) & ~(size_t)255; return p; };
    ushort_t* W2bf   = (ushort_t*)alloc((size_t)1024 * 256 * 2);
    int*      counts = (int*)alloc((size_t)N * 4);
    int*      offs   = (int*)alloc((size_t)(N + 1) * 4);
    int*      cursor = (int*)alloc((size_t)N * 4);
    int*      elist  = (int*)alloc((size_t)E * 4);
    float*    F      = (float*)alloc((size_t)E * 64 * 4);
    (void)ws_size;

    hipMemsetAsync(counts, 0, (size_t)N * 4, stream);
    hipMemsetAsync(cursor, 0, (size_t)N * 4, stream);

    conv_w2<<<256, 256, 0, stream>>>(W2, W2bf);
    hist_kernel<<<(E + 255) / 256, 256, 0, stream>>>(edge_dst, counts, E);
    scan_kernel<<<1, 1024, 0, stream>>>(counts, offs, N);
    fill_kernel<<<(E + 255) / 256, 256, 0, stream>>>(edge_dst, offs, cursor, elist, E);

    const int blocks = (E + TE - 1) / TE;
    nequip_mfma<<<blocks, NTHR, 0, stream>>>(
        node_features, edge_attr, edge_emb, W1, b1, W2bf, b2,
        edge_src, F, E, CC);

    gather_kernel<<<(N + 3) / 4, 256, 0, stream>>>(F, offs, elist, out, N);
}

// Round 11
// 366.338 us; speedup vs baseline: 1.4866x; 1.4866x over previous
//
#include <hip/hip_runtime.h>
#include <math.h>

// ---------------------------------------------------------------------------
// NequIP fused, round 10: grouping win, ported to the 256-thread regime.
//
// R9 post-mortem: 512-thr blocks get a hard 64-VGPR schedule (3rd data point)
// -> G=4 spilled (FETCH/WRITE 200/215MB). 256-thr blocks reliably get ~100.
// This round: 256 thr, wave = slab, all 4 m-tiles per wave.
//   ss/vv/sv: G=2 n-tiles/group: per kk 4 A ds_reads (shared) + 2 B -> 8 MFMA
//   vs:       G=1 (48-reg partials): per kk 4 A + 1 B -> 4 MFMA
// Per-block: A reads 2048->1280, B loads 1024->512 (zero redundancy).
// Single top-level barrier between publish and combine.
// ---------------------------------------------------------------------------

typedef __attribute__((ext_vector_type(8))) short s8v;    // 8 x bf16 (4 VGPR)
typedef __attribute__((ext_vector_type(4))) float f4v;    // 16x16 acc (4 f32)
typedef unsigned short ushort_t;
typedef unsigned int uint_t;

#define NTHR 256
#define TE 64

__device__ __forceinline__ ushort_t f2bf(float x) {
    uint_t u = __float_as_uint(x);
    u += 0x7fffu + ((u >> 16) & 1u);   // round-to-nearest-even
    return (ushort_t)(u >> 16);
}

// W2 [256][1024] fp32 -> W2bf [1024][256] bf16 (transposed, k-contiguous).
__global__ void conv_w2(const float* __restrict__ W2, ushort_t* __restrict__ W2bf) {
    int idx = blockIdx.x * 256 + threadIdx.x;      // 65536 threads, 4 k each
    int n  = idx & 1023;
    int k4 = (idx >> 10) << 2;
    uint_t lo = (uint_t)f2bf(W2[(size_t)(k4 + 0) * 1024 + n]) |
                ((uint_t)f2bf(W2[(size_t)(k4 + 1) * 1024 + n]) << 16);
    uint_t hi = (uint_t)f2bf(W2[(size_t)(k4 + 2) * 1024 + n]) |
                ((uint_t)f2bf(W2[(size_t)(k4 + 3) * 1024 + n]) << 16);
    ((uint2*)W2bf)[(n * 256 + k4) >> 2] = make_uint2(lo, hi);
}

// ---------------- CSR build ----------------
__global__ void hist_kernel(const int* __restrict__ edst, int* __restrict__ counts, int E) {
    int i = blockIdx.x * 256 + threadIdx.x;
    if (i < E) atomicAdd(&counts[edst[i]], 1);
}

__global__ __launch_bounds__(1024)
void scan_kernel(const int* __restrict__ counts, int* __restrict__ offsets, int N) {
    __shared__ int sdata[1024];
    const int t = threadIdx.x;
    const int C = (N + 1023) / 1024;
    const int lo = t * C;
    const int hi = min(lo + C, N);
    int sum = 0;
    for (int i = lo; i < hi; ++i) sum += counts[i];
    sdata[t] = sum;
    __syncthreads();
    for (int s = 1; s < 1024; s <<= 1) {
        int v = (t >= s) ? sdata[t - s] : 0;
        __syncthreads();
        sdata[t] += v;
        __syncthreads();
    }
    int run = sdata[t] - sum;
    for (int i = lo; i < hi; ++i) { offsets[i] = run; run += counts[i]; }
    if (t == 1023) offsets[N] = run;
}

__global__ void fill_kernel(const int* __restrict__ edst,
                            const int* __restrict__ offsets,
                            int* __restrict__ cursor,
                            int* __restrict__ elist, int E) {
    int i = blockIdx.x * 256 + threadIdx.x;
    if (i < E) {
        int d = edst[i];
        int pos = offsets[d] + atomicAdd(&cursor[d], 1);
        elist[pos] = i;
    }
}

// ---------------- gather: one wave per node ----------------
__global__ __launch_bounds__(256)
void gather_kernel(const float* __restrict__ F,
                   const int* __restrict__ offsets,
                   const int* __restrict__ elist,
                   float* __restrict__ out, int N) {
    const int lane = threadIdx.x & 63;
    const int node = (blockIdx.x * 256 + threadIdx.x) >> 6;
    if (node >= N) return;
    const int base = offsets[node];
    const int end  = offsets[node + 1];
    float acc = 0.f;
    for (int j0 = base; j0 < end; j0 += 64) {
        const int rem = min(64, end - j0);
        int myeid = (lane < rem) ? elist[j0 + lane] : 0;
        int j = 0;
        for (; j + 4 <= rem; j += 4) {
            const int a0 = __shfl(myeid, j    );
            const int a1 = __shfl(myeid, j + 1);
            const int a2 = __shfl(myeid, j + 2);
            const int a3 = __shfl(myeid, j + 3);
            const float r0 = F[(size_t)a0 * 64 + lane];
            const float r1 = F[(size_t)a1 * 64 + lane];
            const float r2 = F[(size_t)a2 * 64 + lane];
            const float r3 = F[(size_t)a3 * 64 + lane];
            acc += (r0 + r1) + (r2 + r3);
        }
        for (; j < rem; ++j) {
            const int a = __shfl(myeid, j);
            acc += F[(size_t)a * 64 + lane];
        }
    }
    out[(size_t)node * 64 + lane] = acc;
}

// ---------------- main fused edge kernel (256 thr, 4 waves) ----------------
__global__ __launch_bounds__(NTHR, 2)
void nequip_mfma(const float* __restrict__ nodef,
                 const float* __restrict__ eattr,
                 const float* __restrict__ eemb,
                 const float* __restrict__ W1,
                 const float* __restrict__ b1,
                 const ushort_t* __restrict__ W2bf,
                 const float* __restrict__ b2,
                 const int* __restrict__ esrc,
                 float* __restrict__ F,
                 int E, float CC)
{
    __shared__ __align__(16) ushort_t sAu[TE * 256];   // 32 KB h bf16, A-frag order
    __shared__ __align__(16) float sB2[1024];          // 4 KB
    __shared__ __align__(16) float sEmb[TE * 18];      // 4.5 KB
    __shared__ __align__(16) float sCss[16 * 64];      // coef[i][e] = CC*y0*s
    __shared__ __align__(16) float sCvv[16 * 64];      // CC/sqrt3*(y1.v)
    __shared__ __align__(16) float sCsv[16 * 64];      // CC*s
    __shared__ __align__(16) float sCvs[48 * 64];      // [(i*3+a)][e] = CC*y0*v
    __shared__ __align__(16) float sAttrT[4 * 64];     // [c][e]
    __shared__ __align__(16) float resSS[64 * 16];     // ss partial (4 KB)
    __shared__ __align__(16) float resSV[64 * 16];     // sv partial (4 KB)

    const int t  = threadIdx.x;
    const int e0 = blockIdx.x * TE;

    // ---------------- phase 1: staging + coef tables ----------------
    ((float4*)sB2)[t] = ((const float4*)b2)[t];        // 256 x float4 = 1024
    for (int idx = t; idx < TE * 18; idx += NTHR) {
        size_t g = (size_t)e0 * 18 + idx;
        sEmb[idx] = (g < (size_t)E * 18) ? eemb[g] : 0.f;
    }
    if (t < TE) {
        int ge = e0 + t;
        float4 a = make_float4(0.f, 0.f, 0.f, 0.f);
        if (ge < E) a = *(const float4*)(eattr + (size_t)ge * 4);
        sAttrT[0 * 64 + t] = a.x; sAttrT[1 * 64 + t] = a.y;
        sAttrT[2 * 64 + t] = a.z; sAttrT[3 * 64 + t] = a.w;
    }
    {   // thread t -> edge e = t>>2, i-quad iq = t&3
        const int e = t >> 2, iq = t & 3;
        const int ge = e0 + e;
        const bool ok = ge < E;
        float y0 = 0.f, y1x = 0.f, y1y = 0.f, y1z = 0.f;
        int src = 0;
        if (ok) {
            float4 a = *(const float4*)(eattr + (size_t)ge * 4);
            y0 = a.x; y1x = a.y; y1y = a.z; y1z = a.w;
            src = esrc[ge];
        }
        const float* xp = nodef + (size_t)src * 64;
        float4 z = make_float4(0.f, 0.f, 0.f, 0.f);
        float4 sv = ok ? *(const float4*)(xp + iq * 4) : z;
        float4 v0 = ok ? *(const float4*)(xp + 16 + iq * 12) : z;
        float4 v1 = ok ? *(const float4*)(xp + 16 + iq * 12 + 4) : z;
        float4 v2 = ok ? *(const float4*)(xp + 16 + iq * 12 + 8) : z;
        const float K3 = CC * 0.57735026918962576f;   // CC/sqrt(3)
        float sarr[4] = { sv.x, sv.y, sv.z, sv.w };
        float varr[12] = { v0.x, v0.y, v0.z, v0.w, v1.x, v1.y, v1.z, v1.w,
                           v2.x, v2.y, v2.z, v2.w };
        #pragma unroll
        for (int j = 0; j < 4; ++j) {
            const int i = iq * 4 + j;
            const float s  = sarr[j];
            const float vx = varr[j * 3 + 0], vy = varr[j * 3 + 1], vz = varr[j * 3 + 2];
            sCss[i * 64 + e] = CC * y0 * s;
            sCvv[i * 64 + e] = K3 * (y1x * vx + y1y * vy + y1z * vz);
            sCsv[i * 64 + e] = CC * s;
            sCvs[(i * 3 + 0) * 64 + e] = CC * y0 * vx;
            sCvs[(i * 3 + 1) * 64 + e] = CC * y0 * vy;
            sCvs[(i * 3 + 2) * 64 + e] = CC * y0 * vz;
        }
    }
    __syncthreads();

    // ---- phase 2: h = silu(emb@W1+b1) -> sAu, 16x16x32 A-frag order ----
    // element (e,k): kk=k>>5, lane=(e&15)+16*((k>>3)&3), slot=k&7; lane^kk swizzle
    {
        const int p = t & 127;         // column pair p -> cols 2p, 2p+1
        const int ehalf = t >> 7;
        const int n0 = 2 * p;
        float w1a[18], w1b[18];
        #pragma unroll
        for (int m = 0; m < 18; ++m) {
            float2 wv = *(const float2*)(W1 + m * 256 + n0);
            w1a[m] = wv.x; w1b[m] = wv.y;
        }
        const float2 bv = *(const float2*)(b1 + n0);
        const int kk = p >> 4;                       // k-iter (0..7)
        const int lhi = 16 * ((p >> 2) & 3);
        const int wsub = p & 3;                      // uint slot within 16B frag
        uint_t* sA32 = (uint_t*)sAu;
        for (int er = 0; er < 32; ++er) {
            const int e = ehalf * 32 + er;
            float a0 = bv.x, a1 = bv.y;
            const float* ep = sEmb + e * 18;
            #pragma unroll
            for (int m = 0; m < 18; ++m) {
                const float em = ep[m];
                a0 = fmaf(em, w1a[m], a0);
                a1 = fmaf(em, w1b[m], a1);
            }
            a0 = a0 / (1.f + __expf(-a0));          // silu
            a1 = a1 / (1.f + __expf(-a1));
            const uint_t pk = (uint_t)f2bf(a0) | ((uint_t)f2bf(a1) << 16);
            const int lane_sw = ((e & 15) + lhi) ^ kk;
            sA32[(((e >> 4) * 8 + kk) * 64 + lane_sw) * 4 + wsub] = pk;
        }
    }
    __syncthreads();

    // ---------------- phase 3: wave = slab; 4 m-tiles per wave ----------------
    const int lane = t & 63;
    const int slab = t >> 6;          // 0:ss 1:vv 2:sv 3:vs
    const int jj   = lane & 15;
    const int q4   = lane >> 4;

    const ushort_t* Bl = W2bf + (size_t)jj * 256 + q4 * 8;  // + nb*256 + kk*32

    float pS[4][4] = {{0.f}};          // ss/vv/sv partials [mt][q]
    float pV[3][4][4] = {{{0.f}}};     // vs partials [a][mt][q]

    if (slab < 3) {
        // ---- G=2: per kk 4 A ds_reads (shared) + 2 B loads -> 8 MFMAs ----
        const float* C = (slab == 0) ? sCss : (slab == 1) ? sCvv : sCsv;
        #pragma unroll 1
        for (int g = 0; g < 8; ++g) {
            const int nb0 = slab * 256 + (2 * g) * 16;
            const int nb1 = nb0 + 16;
            f4v accA[4], accB[4];
            {
                const float bz0 = sB2[nb0 + jj];
                const float bz1 = sB2[nb1 + jj];
                #pragma unroll
                for (int mt = 0; mt < 4; ++mt) {
                    f4v zA; zA[0] = bz0; zA[1] = bz0; zA[2] = bz0; zA[3] = bz0;
                    f4v zB; zB[0] = bz1; zB[1] = bz1; zB[2] = bz1; zB[3] = bz1;
                    accA[mt] = zA; accB[mt] = zB;
                }
            }
            #pragma unroll
            for (int kk = 0; kk < 8; ++kk) {
                const s8v b0 = *(const s8v*)(Bl + (size_t)nb0 * 256 + kk * 32);
                const s8v b1 = *(const s8v*)(Bl + (size_t)nb1 * 256 + kk * 32);
                #pragma unroll
                for (int mt = 0; mt < 4; ++mt) {
                    const s8v a = *(const s8v*)(sAu + ((mt * 8 + kk) * 64 + (lane ^ kk)) * 8);
                    accA[mt] = __builtin_amdgcn_mfma_f32_16x16x32_bf16(a, b0, accA[mt], 0, 0, 0);
                    accB[mt] = __builtin_amdgcn_mfma_f32_16x16x32_bf16(a, b1, accB[mt], 0, 0, 0);
                }
            }
            const int i0 = 2 * g, i1 = 2 * g + 1;
            #pragma unroll
            for (int mt = 0; mt < 4; ++mt) {
                const int ebase = mt * 16 + q4 * 4;
                const float4 c0 = *(const float4*)(C + i0 * 64 + ebase);
                const float4 c1 = *(const float4*)(C + i1 * 64 + ebase);
                pS[mt][0] += c0.x * accA[mt][0] + c1.x * accB[mt][0];
                pS[mt][1] += c0.y * accA[mt][1] + c1.y * accB[mt][1];
                pS[mt][2] += c0.z * accA[mt][2] + c1.z * accB[mt][2];
                pS[mt][3] += c0.w * accA[mt][3] + c1.w * accB[mt][3];
            }
        }
        // publish ss / sv partials
        if (slab == 0) {
            #pragma unroll
            for (int mt = 0; mt < 4; ++mt)
                #pragma unroll
                for (int q = 0; q < 4; ++q)
                    resSS[(mt * 16 + q4 * 4 + q) * 16 + jj] = pS[mt][q];
        } else if (slab == 2) {
            #pragma unroll
            for (int mt = 0; mt < 4; ++mt)
                #pragma unroll
                for (int q = 0; q < 4; ++q)
                    resSV[(mt * 16 + q4 * 4 + q) * 16 + jj] = pS[mt][q];
        }
    } else {
        // ---- vs: G=1 (48-reg partials): per kk 4 A + 1 B -> 4 MFMAs ----
        #pragma unroll 1
        for (int ti = 0; ti < 16; ++ti) {
            const int nb = 3 * 256 + ti * 16;
            f4v acc[4];
            {
                const float bz = sB2[nb + jj];
                #pragma unroll
                for (int mt = 0; mt < 4; ++mt) {
                    f4v z; z[0] = bz; z[1] = bz; z[2] = bz; z[3] = bz;
                    acc[mt] = z;
                }
            }
            #pragma unroll
            for (int kk = 0; kk < 8; ++kk) {
                const s8v b = *(const s8v*)(Bl + (size_t)nb * 256 + kk * 32);
                #pragma unroll
                for (int mt = 0; mt < 4; ++mt) {
                    const s8v a = *(const s8v*)(sAu + ((mt * 8 + kk) * 64 + (lane ^ kk)) * 8);
                    acc[mt] = __builtin_amdgcn_mfma_f32_16x16x32_bf16(a, b, acc[mt], 0, 0, 0);
                }
            }
            #pragma unroll
            for (int mt = 0; mt < 4; ++mt) {
                const int ebase = mt * 16 + q4 * 4;
                #pragma unroll
                for (int a = 0; a < 3; ++a) {
                    const float4 c = *(const float4*)(sCvs + (ti * 3 + a) * 64 + ebase);
                    pV[a][mt][0] = fmaf(c.x, acc[mt][0], pV[a][mt][0]);
                    pV[a][mt][1] = fmaf(c.y, acc[mt][1], pV[a][mt][1]);
                    pV[a][mt][2] = fmaf(c.z, acc[mt][2], pV[a][mt][2]);
                    pV[a][mt][3] = fmaf(c.w, acc[mt][3], pV[a][mt][3]);
                }
            }
        }
    }
    __syncthreads();

    // ---------------- combine + store to F ----------------
    if (slab == 1) {          // out_s = resSS(ss) + vv partial
        #pragma unroll
        for (int mt = 0; mt < 4; ++mt) {
            #pragma unroll
            for (int q = 0; q < 4; ++q) {
                const int e = mt * 16 + q4 * 4 + q;
                const int ge = e0 + e;
                if (ge < E) F[(size_t)ge * 64 + jj] = resSS[e * 16 + jj] + pS[mt][q];
            }
        }
    } else if (slab == 3) {   // out_v[a] = y1[a]*resSV(sv) + vs partial
        #pragma unroll
        for (int mt = 0; mt < 4; ++mt) {
            #pragma unroll
            for (int q = 0; q < 4; ++q) {
                const int e = mt * 16 + q4 * 4 + q;
                const int ge = e0 + e;
                const float sv = resSV[e * 16 + jj];
                if (ge < E) {
                    #pragma unroll
                    for (int a = 0; a < 3; ++a)
                        F[(size_t)ge * 64 + 16 + jj * 3 + a] =
                            fmaf(sAttrT[(1 + a) * 64 + e], sv, pV[a][mt][q]);
                }
            }
        }
    }
}

extern "C" void kernel_launch(void* const* d_in, const int* in_sizes, int n_in,
                              void* d_out, int out_size, void* d_ws, size_t ws_size,
                              hipStream_t stream)
{
    const float* node_features = (const float*)d_in[0];
    const float* edge_attr     = (const float*)d_in[1];
    const float* edge_emb      = (const float*)d_in[2];
    const float* W1            = (const float*)d_in[3];
    const float* b1            = (const float*)d_in[4];
    const float* W2            = (const float*)d_in[5];
    const float* b2            = (const float*)d_in[6];
    const int*   edge_src      = (const int*)d_in[7];
    const int*   edge_dst      = (const int*)d_in[8];
    float*       out           = (float*)d_out;

    const int E = in_sizes[7];
    const int N = out_size / 64;
    const float num_neigh = (float)E / (float)N;
    const float CC = 0.17677669529663689f / sqrtf(num_neigh);

    // ---- workspace layout ----
    char* ws = (char*)d_ws;
    size_t off = 0;
    auto alloc = [&](size_t bytes) { char* p = ws + off; off = (off + bytes + 255) & ~(size_t)255; return p; };
    ushort_t* W2bf   = (ushort_t*)alloc((size_t)1024 * 256 * 2);
    int*      counts = (int*)alloc((size_t)N * 4);
    int*      offs   = (int*)alloc((size_t)(N + 1) * 4);
    int*      cursor = (int*)alloc((size_t)N * 4);
    int*      elist  = (int*)alloc((size_t)E * 4);
    float*    F      = (float*)alloc((size_t)E * 64 * 4);
    (void)ws_size;

    hipMemsetAsync(counts, 0, (size_t)N * 4, stream);
    hipMemsetAsync(cursor, 0, (size_t)N * 4, stream);

    conv_w2<<<256, 256, 0, stream>>>(W2, W2bf);
    hist_kernel<<<(E + 255) / 256, 256, 0, stream>>>(edge_dst, counts, E);
    scan_kernel<<<1, 1024, 0, stream>>>(counts, offs, N);
    fill_kernel<<<(E + 255) / 256, 256, 0, stream>>>(edge_dst, offs, cursor, elist, E);

    const int blocks = (E + TE - 1) / TE;
    nequip_mfma<<<blocks, NTHR, 0, stream>>>(
        node_features, edge_attr, edge_emb, W1, b1, W2bf, b2,
        edge_src, F, E, CC);

    gather_kernel<<<(N + 3) / 4, 256, 0, stream>>>(F, offs, elist, out, N);
}